// Round 7
// baseline (220.751 us; speedup 1.0000x reference)
//
#include <hip/hip_runtime.h>
#include <hip/hip_bf16.h>
#include <stdint.h>

#define NBROWS 8192           // NB = B*S*T
#define KBOX   36
#define MROWS  (NBROWS * KBOX)  // 294912
#define RPB    1152           // rows per persistent block (= 32 boxes)
#define NTILE  9              // 1152 / 128

typedef __attribute__((ext_vector_type(8))) short bf16x8;  // 8 bf16 = 4 VGPR
typedef __attribute__((ext_vector_type(4))) float f32x4;

__device__ __forceinline__ unsigned short f2bf(float f) {
  unsigned int u = __float_as_uint(f);
  return (unsigned short)((u + 0x7fffu + ((u >> 16) & 1u)) >> 16);  // RNE
}

__device__ __forceinline__ unsigned int pk2(float x, float y) {
  __hip_bfloat16 hx = __float2bfloat16(x);
  __hip_bfloat16 hy = __float2bfloat16(y);
  unsigned short ux, uy;
  __builtin_memcpy(&ux, &hx, 2);
  __builtin_memcpy(&uy, &hy, 2);
  return (unsigned)ux | ((unsigned)uy << 16);
}

// barrier with LDS-visibility only: in-flight global->register loads are NOT drained
#define LGKM_BARRIER() do {                                   \
    asm volatile("s_waitcnt lgkmcnt(0)" ::: "memory");        \
    asm volatile("s_barrier" ::: "memory");                   \
  } while (0)

// ---------------- kernel 0: convert Wv, Wq to bf16 ----------------
__global__ void cvt_kernel(const float* __restrict__ Wv, const float* __restrict__ Wq,
                           unsigned short* __restrict__ wvb, unsigned short* __restrict__ wqb) {
  int i = blockIdx.x * 256 + threadIdx.x;  // 65536 total
  wvb[i] = f2bf(Wv[i]);
  wqb[i] = f2bf(Wq[i]);
}

// ---------------- q-projection GEMM (R5 structure, proven) ----------------
__global__ __launch_bounds__(256, 2)
void qproj_kernel(const float* __restrict__ Amat,
                  const unsigned short* __restrict__ Wbf,
                  const float* __restrict__ bias,
                  const float* __restrict__ wl,
                  float* __restrict__ outp)
{
  __shared__ unsigned short Asm[2][64 * 32];
  __shared__ unsigned short Bsm[2][256 * 32];
  __shared__ float bias_sm[256];
  __shared__ float aux_sm[256];

  const int t    = threadIdx.x;
  const int lane = t & 63;
  const int wid  = t >> 6;
  const int r0   = blockIdx.x * 64;

  bias_sm[t] = bias[t];
  aux_sm[t]  = wl[t];

  const int brow = t >> 2;
  const int bko  = t & 3;
  const int arow = t >> 2;
  const int ako  = t & 3;
  const float* asrc = Amat + (size_t)(r0 + arow) * 256 + ako * 8;
  const int adst_off = arow * 32 + (ako ^ ((arow >> 1) & 3)) * 8;

  f32x4 acc[4][4];
  #pragma unroll
  for (int a = 0; a < 4; ++a)
    #pragma unroll
    for (int b = 0; b < 4; ++b) acc[a][b] = (f32x4)0.f;

  float4 aregA[2], aregB[2];
  uint4  breg[4];

  #pragma unroll
  for (int i = 0; i < 4; ++i)
    breg[i] = *(const uint4*)&Wbf[(brow + i * 64) * 256 + 0 + bko * 8];
  aregA[0] = ((const float4*)(asrc + 0))[0];
  aregA[1] = ((const float4*)(asrc + 0))[1];
  aregB[0] = ((const float4*)(asrc + 32))[0];
  aregB[1] = ((const float4*)(asrc + 32))[1];
  #pragma unroll
  for (int i = 0; i < 4; ++i) {
    int r = brow + i * 64;
    *(uint4*)&Bsm[0][r * 32 + (bko ^ ((r >> 1) & 3)) * 8] = breg[i];
  }
  {
    uint4 pk;
    pk.x = pk2(aregA[0].x, aregA[0].y);
    pk.y = pk2(aregA[0].z, aregA[0].w);
    pk.z = pk2(aregA[1].x, aregA[1].y);
    pk.w = pk2(aregA[1].z, aregA[1].w);
    *(uint4*)&Asm[0][adst_off] = pk;
  }
  LGKM_BARRIER();

  #pragma unroll
  for (int kk = 0; kk < 8; ++kk) {
    const int cur = kk & 1;
    if (kk < 7) {
      const int d0 = (kk + 1) * 32;
      #pragma unroll
      for (int i = 0; i < 4; ++i)
        breg[i] = *(const uint4*)&Wbf[(brow + i * 64) * 256 + d0 + bko * 8];
    }
    if (kk < 6) {
      const int d0 = (kk + 2) * 32;
      float4 t0 = ((const float4*)(asrc + d0))[0];
      float4 t1 = ((const float4*)(asrc + d0))[1];
      if (kk & 1) { aregB[0] = t0; aregB[1] = t1; }
      else        { aregA[0] = t0; aregA[1] = t1; }
    }
    bf16x8 af[4], bfr[4];
    #pragma unroll
    for (int mf = 0; mf < 4; ++mf) {
      int row  = mf * 16 + (lane & 15);
      int phys = (lane >> 4) ^ ((row >> 1) & 3);
      af[mf] = *(const bf16x8*)&Asm[cur][row * 32 + phys * 8];
    }
    #pragma unroll
    for (int nf = 0; nf < 4; ++nf) {
      int col  = wid * 64 + nf * 16 + (lane & 15);
      int phys = (lane >> 4) ^ ((col >> 1) & 3);
      bfr[nf] = *(const bf16x8*)&Bsm[cur][col * 32 + phys * 8];
    }
    #pragma unroll
    for (int mf = 0; mf < 4; ++mf)
      #pragma unroll
      for (int nf = 0; nf < 4; ++nf)
        acc[mf][nf] = __builtin_amdgcn_mfma_f32_16x16x32_bf16(af[mf], bfr[nf], acc[mf][nf], 0, 0, 0);
    if (kk < 7) {
      #pragma unroll
      for (int i = 0; i < 4; ++i) {
        int r = brow + i * 64;
        *(uint4*)&Bsm[1 - cur][r * 32 + (bko ^ ((r >> 1) & 3)) * 8] = breg[i];
      }
      const float4 a0 = (kk & 1) ? aregA[0] : aregB[0];
      const float4 a1 = (kk & 1) ? aregA[1] : aregB[1];
      uint4 pk;
      pk.x = pk2(a0.x, a0.y);
      pk.y = pk2(a0.z, a0.w);
      pk.z = pk2(a1.x, a1.y);
      pk.w = pk2(a1.z, a1.w);
      *(uint4*)&Asm[1 - cur][adst_off] = pk;
      LGKM_BARRIER();
    }
  }

  #pragma unroll
  for (int mf = 0; mf < 4; ++mf)
    #pragma unroll
    for (int nf = 0; nf < 4; ++nf) {
      int col = wid * 64 + nf * 16 + (lane & 15);
      float bb = bias_sm[col];
      float ww = aux_sm[col];
      #pragma unroll
      for (int j = 0; j < 4; ++j) {
        int row = mf * 16 + ((lane >> 4) << 2) + j;
        float x = fmaxf(acc[mf][nf][j] + bb, 0.f) * ww;
        outp[(size_t)(r0 + row) * 256 + col] = x;
      }
    }
}

// ---------------- main: W-resident, BARRIER-FREE K-loop, fused softmax ----------------
// 256 persistent blocks x 512 threads (8 waves: wm=row-half, wn=col-group).
// W (128 KB bf16) resident in LDS (chunk-XOR swizzle, proven R6).
// A-fragments load DIRECTLY global->reg per wave (no A-LDS, no K-step barrier):
// waves free-run; loads issued 1 step ahead, in flight across everything.
// Only sync: one lgkm-only barrier per 128-row tile for the logit reduction.
__global__ __launch_bounds__(512, 2)
void vmain_kernel(const float* __restrict__ v,
                  const unsigned short* __restrict__ Wbf,
                  const float* __restrict__ bv,
                  const float* __restrict__ g,
                  const float* __restrict__ blp,
                  const float* __restrict__ bmask,
                  float* __restrict__ outp)
{
  __shared__ unsigned short Wlds[256 * 256];   // 128 KB, [col][k] chunks swizzled
  __shared__ float partial[2][128 * 4];        // 4 KB, tile-parity ping-pong
  __shared__ float logit_sm[RPB];              // 4.5 KB  (total 136.5 KB)

  const int t    = threadIdx.x;
  const int lane = t & 63;
  const int wid  = t >> 6;
  const int wn   = wid & 3;      // col group (64 cols)
  const int wm   = wid >> 2;     // row half (64 rows)
  const int l15  = lane & 15;
  const int lq   = lane >> 4;
  const int blk  = blockIdx.x;
  const long long rowbase = (long long)blk * RPB;

  // ---- W -> LDS once (swizzled: phys chunk = chk ^ (col&7)).
  #pragma unroll
  for (int p = 0; p < 16; ++p) {
    int flat = p * 512 + t;
    int col  = flat >> 5;
    int chk  = flat & 31;
    uint4 w = *(const uint4*)&Wbf[col * 256 + chk * 8];
    *(uint4*)&Wlds[col * 256 + (chk ^ (col & 7)) * 8] = w;
  }

  float bias_r[4];
  #pragma unroll
  for (int nf = 0; nf < 4; ++nf) bias_r[nf] = bv[wn * 64 + nf * 16 + l15];
  const float blv = blp[0];

  // per-lane A row pointer: rows wm*64 + mf*16 + l15, k-chunk lq*8
  const float* arow0 = v + (rowbase + wm * 64 + l15) * 256 + lq * 8;

  f32x4 acc[4][4];
  float4 pfA[4][2], pfB[4][2];   // A-fragment prefetch, ping-pong, static names

  auto issueFrag = [&](int nt, int nk, float4 (&pf)[4][2]) {
    const float* base = arow0 + nt * 32768 + nk * 32;   // 128 rows * 256 f32 per tile
    #pragma unroll
    for (int mf = 0; mf < 4; ++mf) {
      const float* p = base + mf * 4096;                // 16 rows * 256 f32
      pf[mf][0] = ((const float4*)p)[0];
      pf[mf][1] = ((const float4*)p)[1];
    }
  };

  auto mfmaStep = [&](int kk, float4 (&pf)[4][2]) {
    bf16x8 bfr[4];
    #pragma unroll
    for (int nf = 0; nf < 4; ++nf) {
      int col  = wn * 64 + nf * 16 + l15;
      int phys = (kk * 4 + lq) ^ (col & 7);
      bfr[nf] = *(const bf16x8*)&Wlds[col * 256 + phys * 8];
    }
    #pragma unroll
    for (int mf = 0; mf < 4; ++mf) {
      uint4 pk;
      pk.x = pk2(pf[mf][0].x, pf[mf][0].y);
      pk.y = pk2(pf[mf][0].z, pf[mf][0].w);
      pk.z = pk2(pf[mf][1].x, pf[mf][1].y);
      pk.w = pk2(pf[mf][1].z, pf[mf][1].w);
      bf16x8 af;
      __builtin_memcpy(&af, &pk, 16);
      #pragma unroll
      for (int nf = 0; nf < 4; ++nf)
        acc[mf][nf] = __builtin_amdgcn_mfma_f32_16x16x32_bf16(af, bfr[nf], acc[mf][nf], 0, 0, 0);
    }
  };

  LGKM_BARRIER();          // W resident
  issueFrag(0, 0, pfA);    // prologue prefetch

  #pragma unroll 1
  for (int tile = 0; tile < NTILE; ++tile) {
    #pragma unroll
    for (int a = 0; a < 4; ++a)
      #pragma unroll
      for (int b = 0; b < 4; ++b) acc[a][b] = (f32x4)0.f;

    const bool more = (tile + 1) < NTILE;
    // even kk consume pfA / issue pfB; odd consume pfB / issue pfA
    issueFrag(tile, 1, pfB);  mfmaStep(0, pfA);
    issueFrag(tile, 2, pfA);  mfmaStep(1, pfB);
    issueFrag(tile, 3, pfB);  mfmaStep(2, pfA);
    issueFrag(tile, 4, pfA);  mfmaStep(3, pfB);
    issueFrag(tile, 5, pfB);  mfmaStep(4, pfA);
    issueFrag(tile, 6, pfA);  mfmaStep(5, pfB);
    issueFrag(tile, 7, pfB);  mfmaStep(6, pfA);
    if (more) issueFrag(tile + 1, 0, pfA);
    mfmaStep(7, pfB);

    // ---- per-tile logit epilogue (g direct from global: L2/L3-hot)
    const int m0  = (int)rowbase + tile * 128;
    const int p   = tile & 1;
    #pragma unroll
    for (int mf = 0; mf < 4; ++mf)
      #pragma unroll
      for (int j = 0; j < 4; ++j) {
        int rloc = wm * 64 + mf * 16 + lq * 4 + j;
        int n    = (m0 + rloc) / KBOX;
        float sv = 0.f;
        #pragma unroll
        for (int nf = 0; nf < 4; ++nf) {
          int col = wn * 64 + nf * 16 + l15;
          sv += fmaxf(acc[mf][nf][j] + bias_r[nf], 0.f) * g[(size_t)n * 256 + col];
        }
        sv += __shfl_xor(sv, 1);
        sv += __shfl_xor(sv, 2);
        sv += __shfl_xor(sv, 4);
        sv += __shfl_xor(sv, 8);
        if (l15 == 0) partial[p][rloc * 4 + wn] = sv;
      }
    LGKM_BARRIER();   // lgkm-only: A-prefetch for next tile stays in flight
    if (t < 128) {
      logit_sm[tile * 128 + t] = partial[p][t * 4 + 0] + partial[p][t * 4 + 1]
                               + partial[p][t * 4 + 2] + partial[p][t * 4 + 3] + blv;
    }
  }

  LGKM_BARRIER();   // logit_sm complete

  // ---- fused masked softmax: 32 boxes, 4 per wave
  const int batch = blk >> 1;            // 32 boxes/block, 64 boxes/batch
  #pragma unroll
  for (int i = 0; i < 4; ++i) {
    int bx = wid * 4 + i;
    long long bg = (long long)blk * 32 + bx;
    float mk = 0.f, lv = 0.f;
    if (lane < KBOX) {
      mk = bmask[batch * KBOX + lane];
      lv = logit_sm[bx * KBOX + lane];
    }
    bool act = (lane < KBOX) && (mk > 0.5f);
    float lm = act ? lv : -3.0e38f;
    #pragma unroll
    for (int off = 32; off >= 1; off >>= 1) lm = fmaxf(lm, __shfl_xor(lm, off));
    float e = act ? expf(lv - lm) : 0.f;
    float ssum = e;
    #pragma unroll
    for (int off = 32; off >= 1; off >>= 1) ssum += __shfl_xor(ssum, off);
    if (lane < KBOX) outp[bg * KBOX + lane] = e / ssum;
  }
}

extern "C" void kernel_launch(void* const* d_in, const int* in_sizes, int n_in,
                              void* d_out, int out_size, void* d_ws, size_t ws_size,
                              hipStream_t stream) {
  const float* v        = (const float*)d_in[0];
  const float* q        = (const float*)d_in[1];
  const float* box_mask = (const float*)d_in[2];
  // d_in[3] = tags_attention: all ones by construction -> gather is identity
  const float* Wv = (const float*)d_in[4];
  const float* bv = (const float*)d_in[5];
  const float* Wq = (const float*)d_in[6];
  const float* bq = (const float*)d_in[7];
  const float* Wl = (const float*)d_in[8];
  const float* bl = (const float*)d_in[9];
  float* outp = (float*)d_out;

  char* ws = (char*)d_ws;
  unsigned short* wvb = (unsigned short*)ws;                     // 128 KB
  unsigned short* wqb = (unsigned short*)(ws + 131072);          // 128 KB
  float* g = (float*)(ws + 262144);                              // 8 MB

  cvt_kernel<<<256, 256, 0, stream>>>(Wv, Wq, wvb, wqb);
  qproj_kernel<<<NBROWS / 64, 256, 0, stream>>>(q, wqb, bq, Wl, g);
  vmain_kernel<<<256, 512, 0, stream>>>(v, wvb, bv, g, bl, box_mask, outp);
}

// Round 8
// 182.480 us; speedup vs baseline: 1.2097x; 1.2097x over previous
//
#include <hip/hip_runtime.h>
#include <hip/hip_bf16.h>
#include <stdint.h>

#define NBROWS 8192           // NB = B*S*T
#define KBOX   36
#define MROWS  (NBROWS * KBOX)  // 294912

typedef __attribute__((ext_vector_type(8))) short bf16x8;  // 8 bf16 = 4 VGPR
typedef __attribute__((ext_vector_type(4))) float f32x4;

__device__ __forceinline__ unsigned short f2bf(float f) {
  unsigned int u = __float_as_uint(f);
  return (unsigned short)((u + 0x7fffu + ((u >> 16) & 1u)) >> 16);  // RNE
}

__device__ __forceinline__ unsigned int pk2(float x, float y) {
  __hip_bfloat16 hx = __float2bfloat16(x);
  __hip_bfloat16 hy = __float2bfloat16(y);
  unsigned short ux, uy;
  __builtin_memcpy(&ux, &hx, 2);
  __builtin_memcpy(&uy, &hy, 2);
  return (unsigned)ux | ((unsigned)uy << 16);
}

// ---------------- kernel 0: convert Wv, Wq to bf16 ----------------
__global__ void cvt_kernel(const float* __restrict__ Wv, const float* __restrict__ Wq,
                           unsigned short* __restrict__ wvb, unsigned short* __restrict__ wqb) {
  int i = blockIdx.x * 256 + threadIdx.x;  // 65536 total
  wvb[i] = f2bf(Wv[i]);
  wqb[i] = f2bf(Wq[i]);
}

// ------------- full-K-resident GEMM: stream-stage A once, barrier-free K-loop -------------
// MODE 0 (qproj): BM=32, A=q, out g[n,h] = relu(acc+bq[h]) * Wl[h], grid 256
// MODE 1 (vmain): BM=64, A=v, out logits[r] = sum_h relu(acc+bv[h]) * g[r/36,h] + bl, grid 4608
// 512 threads = 8 waves (wn=wid&3: 64-col group; wm=wid>>2: row half).
// Phase 1 (stream): each wave loads whole contiguous 1KB rows (lane*16B), all K at once,
//   cvt->bf16->LDS (XOR-swizzled). Deep in-flight, coalesced, m13-copy-like.
// Phase 2 (compute): A from LDS (resident), B-frags DIRECT from L2-hot W (no B-LDS),
//   zero barriers, zero HBM deps. acc 2x4 per wave -> ~4 waves/SIMD occupancy.
template<int MODE>
__global__ __launch_bounds__(512, 4)
void gemm2_kernel(const float* __restrict__ Amat,
                  const unsigned short* __restrict__ Wbf,   // 256x256 bf16 [h][d]
                  const float* __restrict__ bias,           // 256
                  const float* __restrict__ wl,             // 256 (MODE 0)
                  const float* __restrict__ g,              // 8192x256 f32 (MODE 1)
                  const float* __restrict__ blp,            // scalar (MODE 1)
                  float* __restrict__ outp)
{
  constexpr int BM = MODE ? 64 : 32;
  constexpr int MF = MODE ? 2 : 1;      // m-frags per wave
  constexpr int RW = BM / 8;            // rows staged per wave

  __shared__ unsigned short Asm[BM * 256];          // bf16 [row][k], chunk-swizzled
  __shared__ float gtile[MODE ? 3 * 256 : 4];
  __shared__ float partial[MODE ? 64 * 4 : 4];

  const int t    = threadIdx.x;
  const int lane = t & 63;
  const int wid  = t >> 6;
  const int wn   = wid & 3;
  const int wm   = wid >> 2;
  const int l15  = lane & 15;
  const int lq   = lane >> 4;
  const int r0   = blockIdx.x * BM;

  int n0 = 0;
  if (MODE == 1) {
    n0 = r0 / KBOX;
    int n = n0 + (t >> 8);
    if (n > NBROWS - 1) n = NBROWS - 1;
    gtile[t] = g[(size_t)n * 256 + (t & 255)];
    if (t < 256) {
      int n2 = n0 + 2;
      if (n2 > NBROWS - 1) n2 = NBROWS - 1;
      gtile[512 + t] = g[(size_t)n2 * 256 + t];
    }
  }

  float bias_r[4], wl_r[4];
  #pragma unroll
  for (int nf = 0; nf < 4; ++nf) {
    int col = wn * 64 + nf * 16 + l15;
    bias_r[nf] = bias[col];
    wl_r[nf]   = (MODE == 0) ? wl[col] : 0.f;
  }
  const float blv = (MODE == 1) ? blp[0] : 0.f;

  // ---- Phase 1: stream-stage A (whole rows, all K). Wave wid stages rows [wid*RW, +RW).
  {
    float4 st[RW];
    const float* base = Amat + (size_t)(r0 + wid * RW) * 256 + lane * 4;
    #pragma unroll
    for (int i = 0; i < RW; ++i) st[i] = *(const float4*)(base + i * 256);
    #pragma unroll
    for (int i = 0; i < RW; ++i) {
      int r = wid * RW + i;
      uint2 w;
      w.x = pk2(st[i].x, st[i].y);
      w.y = pk2(st[i].z, st[i].w);
      // logical 16B chunk lane>>1  -> phys = (lane>>1) ^ (r&7); +4-short for odd lanes
      *(uint2*)&Asm[r * 256 + (((lane >> 1) ^ (r & 7)) << 3) + ((lane & 1) << 2)] = w;
    }
  }

  // B(0) prefetch before the barrier (regs already hold data after drain)
  uint4 bA[4], bB[4];
  #define LOADB(kk, b)                                                              \
    _Pragma("unroll")                                                               \
    for (int nf = 0; nf < 4; ++nf)                                                  \
      b[nf] = *(const uint4*)&Wbf[(size_t)(wn * 64 + nf * 16 + l15) * 256 + (kk) * 32 + lq * 8];
  LOADB(0, bA);
  __syncthreads();

  f32x4 acc[MF][4];
  #pragma unroll
  for (int mf = 0; mf < MF; ++mf)
    #pragma unroll
    for (int nf = 0; nf < 4; ++nf) acc[mf][nf] = (f32x4)0.f;

  // ---- Phase 2: barrier-free K-loop. A resident in LDS; B direct from L2-hot W.
  #define STEP(kk, bc, bn, prefetch)                                                \
    do {                                                                            \
      if (prefetch) { LOADB((kk) + 1, bn); }                                        \
      bf16x8 af[MF];                                                                \
      _Pragma("unroll")                                                             \
      for (int mf = 0; mf < MF; ++mf) {                                             \
        int row = wm * (16 * MF) + mf * 16 + l15;                                   \
        af[mf] = *(const bf16x8*)&Asm[row * 256 + ((((kk) * 4 + lq) ^ (row & 7)) << 3)]; \
      }                                                                             \
      _Pragma("unroll")                                                             \
      for (int mf = 0; mf < MF; ++mf)                                               \
        _Pragma("unroll")                                                           \
        for (int nf = 0; nf < 4; ++nf) {                                            \
          bf16x8 bb;                                                                \
          __builtin_memcpy(&bb, &bc[nf], 16);                                       \
          acc[mf][nf] = __builtin_amdgcn_mfma_f32_16x16x32_bf16(af[mf], bb, acc[mf][nf], 0, 0, 0); \
        }                                                                           \
    } while (0)

  STEP(0, bA, bB, true);
  STEP(1, bB, bA, true);
  STEP(2, bA, bB, true);
  STEP(3, bB, bA, true);
  STEP(4, bA, bB, true);
  STEP(5, bB, bA, true);
  STEP(6, bA, bB, true);
  STEP(7, bB, bA, false);

  // ---- epilogue. C/D layout: col = lane&15, row = (lane>>4)*4 + j  [m89-verified]
  if (MODE == 0) {
    #pragma unroll
    for (int mf = 0; mf < MF; ++mf)
      #pragma unroll
      for (int nf = 0; nf < 4; ++nf) {
        int col = wn * 64 + nf * 16 + l15;
        #pragma unroll
        for (int j = 0; j < 4; ++j) {
          int row = r0 + wm * (16 * MF) + mf * 16 + lq * 4 + j;
          outp[(size_t)row * 256 + col] = fmaxf(acc[mf][nf][j] + bias_r[nf], 0.f) * wl_r[nf];
        }
      }
  } else {
    #pragma unroll
    for (int mf = 0; mf < MF; ++mf)
      #pragma unroll
      for (int j = 0; j < 4; ++j) {
        int rloc = wm * (16 * MF) + mf * 16 + lq * 4 + j;
        int nl   = (r0 + rloc) / KBOX - n0;            // 0..2
        const float* grow = &gtile[nl * 256];
        float sv = 0.f;
        #pragma unroll
        for (int nf = 0; nf < 4; ++nf) {
          int col = wn * 64 + nf * 16 + l15;
          sv += fmaxf(acc[mf][nf][j] + bias_r[nf], 0.f) * grow[col];
        }
        sv += __shfl_xor(sv, 1);
        sv += __shfl_xor(sv, 2);
        sv += __shfl_xor(sv, 4);
        sv += __shfl_xor(sv, 8);
        if (l15 == 0) partial[rloc * 4 + wn] = sv;
      }
    __syncthreads();
    if (t < 64) {
      outp[r0 + t] = partial[t * 4 + 0] + partial[t * 4 + 1]
                   + partial[t * 4 + 2] + partial[t * 4 + 3] + blv;
    }
  }
  #undef STEP
  #undef LOADB
}

// ---------------- masked softmax over K=36, one wave per row ----------------
__global__ __launch_bounds__(256)
void softmax_kernel(const float* __restrict__ logits, const float* __restrict__ box_mask,
                    float* __restrict__ outp) {
  int n = blockIdx.x * 4 + (threadIdx.x >> 6);
  int k = threadIdx.x & 63;
  int b = n >> 6;  // n / (S*T) = n/64
  float l = 0.f, m = 0.f;
  if (k < KBOX) {
    m = box_mask[b * KBOX + k];
    l = logits[(size_t)n * KBOX + k];
  }
  bool act = (k < KBOX) && (m > 0.5f);
  float lm = act ? l : -3.0e38f;
  #pragma unroll
  for (int off = 32; off >= 1; off >>= 1) lm = fmaxf(lm, __shfl_xor(lm, off));
  float e = act ? expf(l - lm) : 0.f;
  float ssum = e;
  #pragma unroll
  for (int off = 32; off >= 1; off >>= 1) ssum += __shfl_xor(ssum, off);
  if (k < KBOX) outp[(size_t)n * KBOX + k] = e / ssum;
}

extern "C" void kernel_launch(void* const* d_in, const int* in_sizes, int n_in,
                              void* d_out, int out_size, void* d_ws, size_t ws_size,
                              hipStream_t stream) {
  const float* v        = (const float*)d_in[0];
  const float* q        = (const float*)d_in[1];
  const float* box_mask = (const float*)d_in[2];
  // d_in[3] = tags_attention: all ones by construction -> gather is identity
  const float* Wv = (const float*)d_in[4];
  const float* bv = (const float*)d_in[5];
  const float* Wq = (const float*)d_in[6];
  const float* bq = (const float*)d_in[7];
  const float* Wl = (const float*)d_in[8];
  const float* bl = (const float*)d_in[9];
  float* outp = (float*)d_out;

  char* ws = (char*)d_ws;
  unsigned short* wvb = (unsigned short*)ws;                     // 128 KB
  unsigned short* wqb = (unsigned short*)(ws + 131072);          // 128 KB
  float* g      = (float*)(ws + 262144);                         // 8 MB
  float* logits = (float*)(ws + 262144 + 8388608);               // 1.18 MB

  cvt_kernel<<<256, 256, 0, stream>>>(Wv, Wq, wvb, wqb);
  gemm2_kernel<0><<<NBROWS / 32, 512, 0, stream>>>(q, wqb, bq, Wl, nullptr, nullptr, g);
  gemm2_kernel<1><<<MROWS / 64, 512, 0, stream>>>(v, wvb, bv, nullptr, g, bl, logits);
  softmax_kernel<<<NBROWS / 4, 256, 0, stream>>>(logits, box_mask, outp);
}

// Round 9
// 131.923 us; speedup vs baseline: 1.6733x; 1.3832x over previous
//
#include <hip/hip_runtime.h>
#include <hip/hip_bf16.h>
#include <stdint.h>

#define NBROWS 8192           // NB = B*S*T
#define KBOX   36
#define MROWS  (NBROWS * KBOX)  // 294912

typedef __attribute__((ext_vector_type(8))) short bf16x8;  // 8 bf16 = 4 VGPR
typedef __attribute__((ext_vector_type(4))) float f32x4;

__device__ __forceinline__ unsigned short f2bf(float f) {
  unsigned int u = __float_as_uint(f);
  return (unsigned short)((u + 0x7fffu + ((u >> 16) & 1u)) >> 16);  // RNE
}

__device__ __forceinline__ unsigned int pk2(float x, float y) {
  __hip_bfloat16 hx = __float2bfloat16(x);
  __hip_bfloat16 hy = __float2bfloat16(y);
  unsigned short ux, uy;
  __builtin_memcpy(&ux, &hx, 2);
  __builtin_memcpy(&uy, &hy, 2);
  return (unsigned)ux | ((unsigned)uy << 16);
}

// barrier with LDS-visibility only: in-flight global->register loads are NOT drained
#define LGKM_BARRIER() do {                                   \
    asm volatile("s_waitcnt lgkmcnt(0)" ::: "memory");        \
    asm volatile("s_barrier" ::: "memory");                   \
  } while (0)

// ---------------- kernel 0: convert Wv, Wq to bf16 ----------------
__global__ void cvt_kernel(const float* __restrict__ Wv, const float* __restrict__ Wq,
                           unsigned short* __restrict__ wvb, unsigned short* __restrict__ wqb) {
  int i = blockIdx.x * 256 + threadIdx.x;  // 65536 total
  wvb[i] = f2bf(Wv[i]);
  wqb[i] = f2bf(Wq[i]);
}

// ---------------- occupancy-first GEMM: R5 schedule + 24 waves/CU ----------------
// MODE 0: BM=32, A=q, out g[n,h] = relu(acc+bq)*Wl[h], grid 256
// MODE 1: BM=64, A=v, out logits[r] = sum_h relu(acc+bv)*g[r/36,h] + bl, grid 4608
// 512 threads = 8 waves (wm: row-half, wn: 64-col group). A+B double-buffered LDS,
// write-late, lgkm-only barriers (1/step). A-ring depth 3 (2-step flight > HBM lat).
// LDS 44KB -> 3 blocks/CU; launch_bounds caps VGPR at 85 to keep 24 waves/CU.
template<int MODE>
__global__ __launch_bounds__(512, 6)
void gemm3_kernel(const float* __restrict__ Amat,
                  const unsigned short* __restrict__ Wbf,   // 256x256 bf16 [h][d]
                  const float* __restrict__ bias,
                  const float* __restrict__ wl,             // MODE 0
                  const float* __restrict__ g,              // MODE 1
                  const float* __restrict__ blp,            // MODE 1
                  float* __restrict__ outp)
{
  constexpr int BM = MODE ? 64 : 32;
  constexpr int MF = MODE ? 2 : 1;

  __shared__ unsigned short Asm[2][BM * 32];     // 2x(4|2) KB
  __shared__ unsigned short Bsm[2][256 * 32];    // 2x16 KB
  __shared__ float gtile[MODE ? 3 * 256 : 1];
  __shared__ float partial[MODE ? BM * 4 : 1];

  const int t    = threadIdx.x;
  const int lane = t & 63;
  const int wid  = t >> 6;
  const int wn   = wid & 3;
  const int wm   = wid >> 2;
  const int l15  = lane & 15;
  const int lq   = lane >> 4;
  const int r0   = blockIdx.x * BM;

  int n0 = 0;
  if (MODE == 1) {
    n0 = r0 / KBOX;
    {
      int n = n0 + (t >> 8);
      if (n > NBROWS - 1) n = NBROWS - 1;
      gtile[t] = g[(size_t)n * 256 + (t & 255)];
    }
    if (t < 256) {
      int n = n0 + 2;
      if (n > NBROWS - 1) n = NBROWS - 1;
      gtile[512 + t] = g[(size_t)n * 256 + t];
    }
  }

  float bias_r[4], wl_r[4];
  #pragma unroll
  for (int nf = 0; nf < 4; ++nf) {
    int col = wn * 64 + nf * 16 + l15;
    bias_r[nf] = bias[col];
    wl_r[nf]   = (MODE == 0) ? wl[col] : 0.f;
  }
  const float blv = (MODE == 1) ? blp[0] : 0.f;

  // ---- A staging geometry ----
  // MODE1: all 512 threads, 16B f32 each: row=t>>3 (0..63), 16B-seg ac8=t&7 (8x4 f32)
  // MODE0: threads t<256, 16B f32 each: row=t>>3 (0..31), seg t&7
  const int  arow  = t >> 3;
  const int  ac8   = t & 7;
  const bool astg  = (MODE == 1) || (t < 256);
  const float* asrc = Amat + (size_t)(r0 + (arow & (BM - 1))) * 256 + ac8 * 4;
  // swizzle: 16B chunk c -> c ^ swz(row); MODE1 swz=(row>>1)&3, MODE0 swz=row&3
  const int  aswz  = MODE ? ((arow >> 1) & 3) : (arow & 3);
  const int  adst  = (arow & (BM - 1)) * 32 + (((ac8 >> 1) ^ aswz) << 3) + ((ac8 & 1) << 2); // shorts

  // ---- B staging geometry: all threads, 2 x uint4: rows h, h+128, chunk bko ----
  const int bh0 = t >> 2;          // 0..127
  const int bko = t & 3;
  const int bd0 = bh0 * 32 + ((bko ^ ((bh0 >> 1) & 3)) << 3);
  const int bh1 = bh0 + 128;
  const int bd1 = bh1 * 32 + ((bko ^ ((bh1 >> 1) & 3)) << 3);

  f32x4 acc[MF][4];
  #pragma unroll
  for (int mf = 0; mf < MF; ++mf)
    #pragma unroll
    for (int nf = 0; nf < 4; ++nf) acc[mf][nf] = (f32x4)0.f;

  float4 s0, s1, s2;        // A prefetch ring, depth 3
  uint4  breg0, breg1;      // B prefetch, depth 1

  #define AISS(slot, kk)  do { if (astg) slot = *(const float4*)(asrc + (kk) * 32); } while (0)
  #define ACVT(slot, buf) do { if (astg) {                                        \
      uint2 w_;                                                                   \
      w_.x = pk2(slot.x, slot.y);                                                 \
      w_.y = pk2(slot.z, slot.w);                                                 \
      *(uint2*)&Asm[buf][adst] = w_; } } while (0)
  #define BISS(kk) do {                                                           \
      breg0 = *(const uint4*)&Wbf[(size_t)bh0 * 256 + (kk) * 32 + bko * 8];       \
      breg1 = *(const uint4*)&Wbf[(size_t)bh1 * 256 + (kk) * 32 + bko * 8]; } while (0)
  #define BWRT(buf) do {                                                          \
      *(uint4*)&Bsm[buf][bd0] = breg0;                                            \
      *(uint4*)&Bsm[buf][bd1] = breg1; } while (0)

  // ---- prologue: A0,A1,A2 + B0 in flight; A0,B0 -> LDS buf0 ----
  AISS(s0, 0);
  AISS(s1, 1);
  AISS(s2, 2);
  BISS(0);
  ACVT(s0, 0);
  BWRT(0);
  LGKM_BARRIER();   // A1,A2 global loads stay in flight

  #define STEP(kk, PISS, PCVT, DO_ISS, DO_NXT)                                    \
  do {                                                                            \
    if (DO_ISS) AISS(PISS, (kk) + 3);                                             \
    if (DO_NXT) BISS((kk) + 1);                                                   \
    bf16x8 af[MF], bfr[4];                                                        \
    _Pragma("unroll")                                                             \
    for (int mf = 0; mf < MF; ++mf) {                                             \
      int row  = wm * (BM / 2) + mf * 16 + l15;                                   \
      int phys = lq ^ (MODE ? ((row >> 1) & 3) : (row & 3));                      \
      af[mf] = *(const bf16x8*)&Asm[(kk) & 1][row * 32 + phys * 8];               \
    }                                                                             \
    _Pragma("unroll")                                                             \
    for (int nf = 0; nf < 4; ++nf) {                                              \
      int col  = wn * 64 + nf * 16 + l15;                                         \
      int phys = lq ^ ((col >> 1) & 3);                                           \
      bfr[nf] = *(const bf16x8*)&Bsm[(kk) & 1][col * 32 + phys * 8];              \
    }                                                                             \
    _Pragma("unroll")                                                             \
    for (int mf = 0; mf < MF; ++mf)                                               \
      _Pragma("unroll")                                                           \
      for (int nf = 0; nf < 4; ++nf)                                              \
        acc[mf][nf] = __builtin_amdgcn_mfma_f32_16x16x32_bf16(af[mf], bfr[nf], acc[mf][nf], 0, 0, 0); \
    if (DO_NXT) {                                                                 \
      BWRT(((kk) + 1) & 1);                                                       \
      ACVT(PCVT, ((kk) + 1) & 1);                                                 \
      LGKM_BARRIER();                                                             \
    }                                                                             \
  } while (0)

  STEP(0, s0, s1, true,  true);   // issue A3->s0, cvt A1 (s1)
  STEP(1, s1, s2, true,  true);   // issue A4->s1, cvt A2 (s2)
  STEP(2, s2, s0, true,  true);   // issue A5->s2, cvt A3 (s0)
  STEP(3, s0, s1, true,  true);   // issue A6->s0, cvt A4 (s1)
  STEP(4, s1, s2, true,  true);   // issue A7->s1, cvt A5 (s2)
  STEP(5, s0, s0, false, true);   // cvt A6 (s0)
  STEP(6, s1, s1, false, true);   // cvt A7 (s1)
  STEP(7, s2, s2, false, false);

  #undef STEP
  #undef AISS
  #undef ACVT
  #undef BISS
  #undef BWRT

  // ---- epilogue. C/D layout: col = lane&15, row = (lane>>4)*4 + j [m89-verified]
  if (MODE == 0) {
    #pragma unroll
    for (int mf = 0; mf < MF; ++mf)
      #pragma unroll
      for (int nf = 0; nf < 4; ++nf) {
        int col = wn * 64 + nf * 16 + l15;
        #pragma unroll
        for (int j = 0; j < 4; ++j) {
          int row = r0 + wm * (BM / 2) + mf * 16 + lq * 4 + j;
          outp[(size_t)row * 256 + col] = fmaxf(acc[mf][nf][j] + bias_r[nf], 0.f) * wl_r[nf];
        }
      }
  } else {
    #pragma unroll
    for (int mf = 0; mf < MF; ++mf)
      #pragma unroll
      for (int j = 0; j < 4; ++j) {
        int rloc = wm * 32 + mf * 16 + lq * 4 + j;
        int nl   = (r0 + rloc) / KBOX - n0;            // 0..2
        const float* grow = &gtile[nl * 256];
        float sv = 0.f;
        #pragma unroll
        for (int nf = 0; nf < 4; ++nf) {
          int col = wn * 64 + nf * 16 + l15;
          sv += fmaxf(acc[mf][nf][j] + bias_r[nf], 0.f) * grow[col];
        }
        sv += __shfl_xor(sv, 1);
        sv += __shfl_xor(sv, 2);
        sv += __shfl_xor(sv, 4);
        sv += __shfl_xor(sv, 8);
        if (l15 == 0) partial[rloc * 4 + wn] = sv;
      }
    __syncthreads();
    if (t < BM) {
      outp[r0 + t] = partial[t * 4 + 0] + partial[t * 4 + 1]
                   + partial[t * 4 + 2] + partial[t * 4 + 3] + blv;
    }
  }
}

// ---------------- masked softmax over K=36, one wave per row ----------------
__global__ __launch_bounds__(256)
void softmax_kernel(const float* __restrict__ logits, const float* __restrict__ box_mask,
                    float* __restrict__ outp) {
  int n = blockIdx.x * 4 + (threadIdx.x >> 6);
  int k = threadIdx.x & 63;
  int b = n >> 6;  // n / (S*T) = n/64
  float l = 0.f, m = 0.f;
  if (k < KBOX) {
    m = box_mask[b * KBOX + k];
    l = logits[(size_t)n * KBOX + k];
  }
  bool act = (k < KBOX) && (m > 0.5f);
  float lm = act ? l : -3.0e38f;
  #pragma unroll
  for (int off = 32; off >= 1; off >>= 1) lm = fmaxf(lm, __shfl_xor(lm, off));
  float e = act ? expf(l - lm) : 0.f;
  float ssum = e;
  #pragma unroll
  for (int off = 32; off >= 1; off >>= 1) ssum += __shfl_xor(ssum, off);
  if (k < KBOX) outp[(size_t)n * KBOX + k] = e / ssum;
}

extern "C" void kernel_launch(void* const* d_in, const int* in_sizes, int n_in,
                              void* d_out, int out_size, void* d_ws, size_t ws_size,
                              hipStream_t stream) {
  const float* v        = (const float*)d_in[0];
  const float* q        = (const float*)d_in[1];
  const float* box_mask = (const float*)d_in[2];
  // d_in[3] = tags_attention: all ones by construction -> gather is identity
  const float* Wv = (const float*)d_in[4];
  const float* bv = (const float*)d_in[5];
  const float* Wq = (const float*)d_in[6];
  const float* bq = (const float*)d_in[7];
  const float* Wl = (const float*)d_in[8];
  const float* bl = (const float*)d_in[9];
  float* outp = (float*)d_out;

  char* ws = (char*)d_ws;
  unsigned short* wvb = (unsigned short*)ws;                     // 128 KB
  unsigned short* wqb = (unsigned short*)(ws + 131072);          // 128 KB
  float* g      = (float*)(ws + 262144);                         // 8 MB
  float* logits = (float*)(ws + 262144 + 8388608);               // 1.18 MB

  cvt_kernel<<<256, 256, 0, stream>>>(Wv, Wq, wvb, wqb);
  gemm3_kernel<0><<<NBROWS / 32, 512, 0, stream>>>(q, wqb, bq, Wl, nullptr, nullptr, g);
  gemm3_kernel<1><<<MROWS / 64, 512, 0, stream>>>(v, wvb, bv, nullptr, g, bl, logits);
  softmax_kernel<<<NBROWS / 4, 256, 0, stream>>>(logits, box_mask, outp);
}